// Round 10
// baseline (151.368 us; speedup 1.0000x reference)
//
#include <hip/hip_runtime.h>
#include <hip/hip_bf16.h>
#include <math.h>

#define S 4096
#define CIN 256
#define C3 768
#define NH 8
#define HD 32
#define KSPLIT 4

static constexpr float EPS = 1e-4f;

typedef __attribute__((ext_vector_type(8))) __bf16 bf16x8;
typedef __attribute__((ext_vector_type(4))) float f32x4;
typedef __attribute__((ext_vector_type(16))) float f32x16;
typedef __attribute__((ext_vector_type(8))) unsigned short u16x8;
typedef __attribute__((ext_vector_type(4))) unsigned u32x4;

static inline __device__ ushort f2bf(float f) {  // RN-even
  unsigned u = __float_as_uint(f);
  return (ushort)((u + 0x7fffu + ((u >> 16) & 1u)) >> 16);
}
static inline __device__ float bf2f(ushort u) {
  return __uint_as_float((unsigned)u << 16);
}

// v_cvt_pk_bf16_f32: dst.lo16 = bf16(lo), dst.hi16 = bf16(hi); RNE (no builtin)
static inline __device__ unsigned cvt_pk_bf16(float lo, float hi) {
  unsigned r;
  asm("v_cvt_pk_bf16_f32 %0, %1, %2" : "=v"(r) : "v"(lo), "v"(hi));
  return r;
}
// v_permlane32_swap_b32: a.hi32lanes <-> b.lo32lanes.
static inline __device__ void plane32_swap(unsigned& a, unsigned& b) {
  asm("v_permlane32_swap_b32 %0, %1" : "+v"(a), "+v"(b));
}

#define EXP2 __builtin_amdgcn_exp2f

// All GEMM operands live in [16 rows][32 ch] = 1KB fragment panels:
//   elem (r, c) of tile -> tile_base + (r&15)*32 + (c&31)
//   frag load = tile_base + col*32 + quad*8  (dense 1KB per instruction)

// Convert one 32x32 QK score tile (D-layout: col=q=lane&31, row=k=(r&3)+8*(r>>2)+4*hi)
// to two PV operand fragments (col/row=q, k = frag*8 elements at 8*hi+j) fully
// in registers: 16 exp2 + 8 cvt_pk + 4 permlane32_swap. Denominator is NOT
// summed here -- it rides the MFMA pipe via ones-A MFMA (R10: 124 unified regs
// fit the (256,4) cap, so the 32 VALU adds/iter move to the 25%-busy MFMA pipe).
static inline __device__ void s_to_pf(const f32x16 s, bf16x8& plo, bf16x8& phi) {
  unsigned c0 = cvt_pk_bf16(EXP2(s[0]), EXP2(s[1]));
  unsigned c1 = cvt_pk_bf16(EXP2(s[2]), EXP2(s[3]));
  unsigned c2 = cvt_pk_bf16(EXP2(s[4]), EXP2(s[5]));
  unsigned c3 = cvt_pk_bf16(EXP2(s[6]), EXP2(s[7]));
  plane32_swap(c0, c2);
  plane32_swap(c1, c3);
  u32x4 lo4 = {c0, c1, c2, c3};
  plo = __builtin_bit_cast(bf16x8, lo4);
  unsigned c4 = cvt_pk_bf16(EXP2(s[8]), EXP2(s[9]));
  unsigned c5 = cvt_pk_bf16(EXP2(s[10]), EXP2(s[11]));
  unsigned c6 = cvt_pk_bf16(EXP2(s[12]), EXP2(s[13]));
  unsigned c7 = cvt_pk_bf16(EXP2(s[14]), EXP2(s[15]));
  plane32_swap(c4, c6);
  plane32_swap(c5, c7);
  u32x4 hi4 = {c4, c5, c6, c7};
  phi = __builtin_bit_cast(bf16x8, hi4);
}

// ---------------- weight norm -> 16x32 fragment panels -----------------------
__global__ __launch_bounds__(256) void wnorm_kernel(const float* __restrict__ w_qkv,
                                                    const float* __restrict__ w_out,
                                                    ushort* __restrict__ wqb,
                                                    ushort* __restrict__ wob) {
  const int row = blockIdx.x * 4 + (threadIdx.x >> 6);
  const int lane = threadIdx.x & 63;
  const bool is_q = row < C3;
  const int r2 = is_q ? row : row - C3;
  const float* wr = (is_q ? w_qkv : w_out) + (size_t)r2 * CIN;
  float v[4];
  #pragma unroll
  for (int i = 0; i < 4; i++) v[i] = wr[lane + 64 * i];
  float ss = v[0] * v[0] + v[1] * v[1] + v[2] * v[2] + v[3] * v[3];
  #pragma unroll
  for (int off = 32; off > 0; off >>= 1) ss += __shfl_down(ss, off, 64);
  ss = __shfl(ss, 0, 64);
  const float scale = 1.0f / (sqrtf(ss) + 16.0f * EPS);
  ushort* whr = (is_q ? wqb : wob);
  #pragma unroll
  for (int i = 0; i < 4; i++) {
    const int c = lane + 64 * i;
    whr[((size_t)(r2 >> 4) * (CIN / 32) + (c >> 5)) * 512 + (r2 & 15) * 32 + (c & 31)] =
        f2bf(v[i] * scale);
  }
}

// ---------------- X [b][c][s] fp32 -> Xt 16x32 panels ------------------------
__global__ __launch_bounds__(256) void xt_kernel(const float* __restrict__ X,
                                                 ushort* __restrict__ Xt) {
  const int b = blockIdx.z;
  const int s0 = blockIdx.x * 64, c0 = blockIdx.y * 64;
  __shared__ ushort T[64][72];
  const int tc = threadIdx.x >> 4;
  const int ts = threadIdx.x & 15;
  #pragma unroll
  for (int i = 0; i < 4; i++) {
    const float4 v = *(const float4*)&X[((size_t)(b * CIN + c0 + tc + 16 * i)) * S + s0 + ts * 4];
    ushort4 u;
    u.x = f2bf(v.x); u.y = f2bf(v.y); u.z = f2bf(v.z); u.w = f2bf(v.w);
    *(ushort4*)&T[tc + 16 * i][ts * 4] = u;
  }
  __syncthreads();
  #pragma unroll
  for (int i = 0; i < 4; i++) {
    const int sr = tc + 16 * i;
    const int s = s0 + sr;
    const int c = c0 + ts * 4;
    ushort4 u;
    u.x = T[ts * 4 + 0][sr];
    u.y = T[ts * 4 + 1][sr];
    u.z = T[ts * 4 + 2][sr];
    u.w = T[ts * 4 + 3][sr];
    *(ushort4*)&Xt[(((size_t)b * (S / 16) + (s >> 4)) * (CIN / 32) + (c >> 5)) * 512 +
                   (s & 15) * 32 + (c & 31)] = u;
  }
}

// ---------------- conv1 fused with pixel-norm + layout fan-out ---------------
// Wave tile 32m x 32n; block = 2 m-groups x 2 n-tiles = 64m x 64n. Grid
// (64,12,2) = 1536 blocks = 6 blocks/CU (2x R9's TLP at IDENTICAL traffic:
// y-block count stays 12 so B re-read is still 12x, and same-x blocks still
// share an XCD since delta-id = 64 == 0 mod 8). A/B from 16x32 panels.
__global__ __launch_bounds__(256) void conv1_fused_kernel(const ushort* __restrict__ W,
                                                          const ushort* __restrict__ Bm,
                                                          ushort* __restrict__ Qn,
                                                          ushort* __restrict__ Kn,
                                                          ushort* __restrict__ Vt) {
  const int b = blockIdx.z;
  const int wid = threadIdx.x >> 6, lane = threadIdx.x & 63;
  const int col = lane & 15, quad = lane >> 4;
  const int m0 = blockIdx.y * 64 + (wid >> 1) * 32;  // 32-aligned: one head group
  const int n0 = blockIdx.x * 64 + (wid & 1) * 32;
  const ushort* Bb = Bm + (size_t)b * (S / 16) * (CIN / 32) * 512;
  const int lofs = col * 32 + quad * 8;
  f32x4 acc[2][2] = {};
  #pragma unroll
  for (int k0 = 0; k0 < CIN; k0 += 32) {
    bf16x8 af[2], bf[2];
    #pragma unroll
    for (int mi = 0; mi < 2; mi++)
      af[mi] = *(const bf16x8*)&W[((size_t)(m0 / 16 + mi) * (CIN / 32) + (k0 >> 5)) * 512 + lofs];
    #pragma unroll
    for (int ni = 0; ni < 2; ni++)
      bf[ni] = *(const bf16x8*)&Bb[((size_t)(n0 / 16 + ni) * (CIN / 32) + (k0 >> 5)) * 512 + lofs];
    #pragma unroll
    for (int mi = 0; mi < 2; mi++)
      #pragma unroll
      for (int ni = 0; ni < 2; ni++)
        acc[mi][ni] = __builtin_amdgcn_mfma_f32_16x16x32_bf16(af[mi], bf[ni], acc[mi][ni], 0, 0, 0);
  }

  const int g = m0 >> 5;   // 0..23: group; 0-7 Q, 8-15 K, 16-23 V
  const int h = g & 7;
  float rn[2];
  #pragma unroll
  for (int ni = 0; ni < 2; ni++) {
    float ss = 0.f;
    #pragma unroll
    for (int mi = 0; mi < 2; mi++)
      #pragma unroll
      for (int r = 0; r < 4; r++) ss += acc[mi][ni][r] * acc[mi][ni][r];
    ss += __shfl_xor(ss, 16, 64);
    ss += __shfl_xor(ss, 32, 64);
    rn[ni] = rsqrtf(ss * (1.0f / HD) + EPS);
    if (g < 8) rn[ni] *= 0.2550348190698169f;  // log2(e)/sqrt(32) folded into Q
  }

  if (g < 8) {  // Q: row layout [q][HD]
    ushort* dst = Qn + (size_t)(b * NH + h) * S * HD;
    #pragma unroll
    for (int mi = 0; mi < 2; mi++)
      #pragma unroll
      for (int ni = 0; ni < 2; ni++) {
        ushort4 u;
        u.x = f2bf(acc[mi][ni][0] * rn[ni]);
        u.y = f2bf(acc[mi][ni][1] * rn[ni]);
        u.z = f2bf(acc[mi][ni][2] * rn[ni]);
        u.w = f2bf(acc[mi][ni][3] * rn[ni]);
        *(ushort4*)&dst[(size_t)(n0 + ni * 16 + col) * HD + mi * 16 + quad * 4] = u;
      }
  } else if (g < 16) {  // K: attn fragment panels (key = n0+ni*16+col; ch = mi*16+quad*4+r)
    ushort* dst = Kn + (size_t)(b * NH + h) * S * HD + (size_t)(n0 >> 5) * 1024;
    #pragma unroll
    for (int mi = 0; mi < 2; mi++)
      #pragma unroll
      for (int ni = 0; ni < 2; ni++) {
        ushort4 u;
        u.x = f2bf(acc[mi][ni][0] * rn[ni]);
        u.y = f2bf(acc[mi][ni][1] * rn[ni]);
        u.z = f2bf(acc[mi][ni][2] * rn[ni]);
        u.w = f2bf(acc[mi][ni][3] * rn[ni]);
        *(ushort4*)&dst[mi * 512 + (ni * 16 + col) * 16 +
                        (quad >> 1) * 8 + (quad & 1) * 4] = u;
      }
  } else {  // V: attn fragment panels (d = mi*16+quad*4+r, key = n0+ni*16+col)
    ushort* dst = Vt + (size_t)(b * NH + h) * HD * S + (size_t)(n0 >> 6) * 2048;
    const int kcbase = (n0 & 32) >> 4;  // which 16-key slot inside the 64-key panel
    #pragma unroll
    for (int mi = 0; mi < 2; mi++)
      #pragma unroll
      for (int ni = 0; ni < 2; ni++)
        #pragma unroll
        for (int r = 0; r < 4; r++)
          dst[(kcbase + ni) * 512 + (mi * 16 + quad * 4 + r) * 16 + col] =
              f2bf(acc[mi][ni][r] * rn[ni]);
  }
}

// ---------------- MFMA attention: dual 32x32 q-tiles per wave ----------------
// R8 structure + ones-MFMA denominators restored (R10): the 32 VALU adds/iter
// move to the MFMA pipe (25% busy), shortening the VALU chain ~30%.
// Register budget: 60 VGPR + 64 AGPR = 124 <= 128 cap at (256,4) -- residency
// unchanged at 4 waves/SIMD. DO NOT raise waves/EU (R2/R4 spilled at (256,8)).
// KSPLIT=4, grid 1024 = 4 blocks/CU, bijective XCD swizzle, zero LDS, bf16
// partial output. Spill tripwire: WRITE_SIZE must stay ~17.4 MB.
__global__ __launch_bounds__(256, 4) void attn_kernel(const ushort* __restrict__ Qn,
                                                      const ushort* __restrict__ Kn,
                                                      const ushort* __restrict__ Vt,
                                                      ushort* __restrict__ accPb,
                                                      float* __restrict__ lP) {
  const int NWG = (S / 256) * NH * KSPLIT * 2;  // 1024
  const int bid = blockIdx.x;
  const int id = (bid & 7) * (NWG / 8) + (bid >> 3);
  const int qt = id & 15;       // 16 q-tiles of 256 rows
  const int grp = id >> 4;      // ((b*KSPLIT + kp) << 3) | h
  const int h = grp & 7;
  const int kp = (grp >> 3) & (KSPLIT - 1);
  const int b = (grp >> 3) / KSPLIT;
  const int wid = threadIdx.x >> 6, lane = threadIdx.x & 63;
  const int ln = lane & 31, hi = lane >> 5;
  const int qA = qt * 256 + wid * 64;   // tile A rows qA..qA+31
  const int qB = qA + 32;               // tile B rows qB..qB+31

  const ushort* Qh = Qn + (size_t)(b * NH + h) * S * HD;

  // Q as B-frag: col=q=ln, ch = half*16 + 8*hi + j
  bf16x8 qfA0 = *(const bf16x8*)&Qh[(size_t)(qA + ln) * HD + hi * 8];
  bf16x8 qfA1 = *(const bf16x8*)&Qh[(size_t)(qA + ln) * HD + 16 + hi * 8];
  bf16x8 qfB0 = *(const bf16x8*)&Qh[(size_t)(qB + ln) * HD + hi * 8];
  bf16x8 qfB1 = *(const bf16x8*)&Qh[(size_t)(qB + ln) * HD + 16 + hi * 8];

  const u16x8 ou = {0x3F80, 0x3F80, 0x3F80, 0x3F80, 0x3F80, 0x3F80, 0x3F80, 0x3F80};
  const bf16x8 ones = __builtin_bit_cast(bf16x8, ou);
  const f32x16 z = {};
  f32x16 accA = {}, accB = {};    // out^T tiles: row=d, col=q
  f32x16 acclA = {}, acclB = {};  // softmax denoms (all rows identical)

  const int kt0 = kp * (S / KSPLIT);
  // fragment-panel bases; every frag load = base + frag_offset + loff
  const int loff = (ln * 2 + hi) * 8;
  const ushort* Kp = Kn + (size_t)(b * NH + h) * S * HD + (size_t)kt0 * 32 + loff;
  const ushort* Vp = Vt + (size_t)(b * NH + h) * HD * S + (size_t)kt0 * 32 + loff;

  bf16x8 kf0 = *(const bf16x8*)&Kp[0];
  bf16x8 kf1 = *(const bf16x8*)&Kp[512];
  bf16x8 vf0 = *(const bf16x8*)&Vp[0];
  bf16x8 vf1 = *(const bf16x8*)&Vp[512];

  #pragma unroll 1
  for (int it = 0; it < S / KSPLIT / 32; ++it) {   // 32-key steps
    f32x16 sA = __builtin_amdgcn_mfma_f32_32x32x16_bf16(kf0, qfA0, z, 0, 0, 0);
    sA = __builtin_amdgcn_mfma_f32_32x32x16_bf16(kf1, qfA1, sA, 0, 0, 0);
    f32x16 sB = __builtin_amdgcn_mfma_f32_32x32x16_bf16(kf0, qfB0, z, 0, 0, 0);
    sB = __builtin_amdgcn_mfma_f32_32x32x16_bf16(kf1, qfB1, sB, 0, 0, 0);
    Kp += 1024;
    kf0 = *(const bf16x8*)&Kp[0];      // prefetch next tile's K (overread stays in ws)
    kf1 = *(const bf16x8*)&Kp[512];

    bf16x8 pfA0, pfA1;
    s_to_pf(sA, pfA0, pfA1);
    accA = __builtin_amdgcn_mfma_f32_32x32x16_bf16(vf0, pfA0, accA, 0, 0, 0);
    acclA = __builtin_amdgcn_mfma_f32_32x32x16_bf16(ones, pfA0, acclA, 0, 0, 0);
    accA = __builtin_amdgcn_mfma_f32_32x32x16_bf16(vf1, pfA1, accA, 0, 0, 0);
    acclA = __builtin_amdgcn_mfma_f32_32x32x16_bf16(ones, pfA1, acclA, 0, 0, 0);

    bf16x8 pfB0, pfB1;
    s_to_pf(sB, pfB0, pfB1);
    accB = __builtin_amdgcn_mfma_f32_32x32x16_bf16(vf0, pfB0, accB, 0, 0, 0);
    acclB = __builtin_amdgcn_mfma_f32_32x32x16_bf16(ones, pfB0, acclB, 0, 0, 0);
    accB = __builtin_amdgcn_mfma_f32_32x32x16_bf16(vf1, pfB1, accB, 0, 0, 0);
    acclB = __builtin_amdgcn_mfma_f32_32x32x16_bf16(ones, pfB1, acclB, 0, 0, 0);

    Vp += 1024;
    vf0 = *(const bf16x8*)&Vp[0];      // prefetch next tile's V
    vf1 = *(const bf16x8*)&Vp[512];
  }

  // acc[r]: d = (r&3) + 8*(r>>2) + 4*hi, q = ln; pack f32 pairs -> bf16
  ushort* ap = accPb + ((size_t)((kp * 2 + b) * NH + h)) * S * HD;
  const size_t rowA = (size_t)(qA + ln) * HD;
  const size_t rowB = (size_t)(qB + ln) * HD;
  #pragma unroll
  for (int g = 0; g < 4; g++) {
    uint2 u;
    u.x = cvt_pk_bf16(accA[4 * g + 0], accA[4 * g + 1]);
    u.y = cvt_pk_bf16(accA[4 * g + 2], accA[4 * g + 3]);
    *(uint2*)&ap[rowA + g * 8 + hi * 4] = u;
    uint2 v;
    v.x = cvt_pk_bf16(accB[4 * g + 0], accB[4 * g + 1]);
    v.y = cvt_pk_bf16(accB[4 * g + 2], accB[4 * g + 3]);
    *(uint2*)&ap[rowB + g * 8 + hi * 4] = v;
  }
  if (hi == 0) {
    float* lp = lP + ((size_t)((kp * 2 + b) * NH + h)) * S;
    lp[qA + ln] = acclA[0];
    lp[qB + ln] = acclB[0];
  }
}

// ---------------- combine K-split partials (bf16) -> Yt 16x32 panels ---------
__global__ __launch_bounds__(256) void combine_kernel(const ushort* __restrict__ accPb,
                                                      const float* __restrict__ lP,
                                                      ushort* __restrict__ Yt) {
  const int tid = blockIdx.x * 256 + threadIdx.x;
  const int dg = tid & 7;
  const int q = (tid >> 3) & (S - 1);
  const int h = (tid >> 15) & 7;
  const int b = tid >> 18;
  const size_t i0 = ((size_t)(b * NH + h)) * S + q;
  const size_t part = (size_t)2 * NH * S;
  float sx = 0.f, sy = 0.f, sz = 0.f, sw = 0.f, L = 0.f;
  #pragma unroll
  for (int p = 0; p < KSPLIT; p++) {
    const ushort4 a = *(const ushort4*)&accPb[(size_t)p * part * HD + i0 * HD + dg * 4];
    sx += bf2f(a.x); sy += bf2f(a.y); sz += bf2f(a.z); sw += bf2f(a.w);
    L += lP[(size_t)p * part + i0];
  }
  const float rl = 1.0f / L;
  ushort4 o;
  o.x = f2bf(sx * rl);
  o.y = f2bf(sy * rl);
  o.z = f2bf(sz * rl);
  o.w = f2bf(sw * rl);
  // Yt panel: row=q, ch tile = h (c = h*32 + dg*4)
  *(ushort4*)&Yt[(((size_t)b * (S / 16) + (q >> 4)) * (CIN / 32) + h) * 512 +
                 (q & 15) * 32 + dg * 4] = o;
}

// ---------------- conv2: OUT[b][m][s] fp32 = Wo . Yt, fused mp_add -----------
// A (Wo) and B (Yt) from 16x32 panels (dense frag loads). Block = 4 waves
// covering 64m x 64n. Grid (64,4,2) = 512 blocks = 2 blocks/CU (R8/R9 config).
__global__ __launch_bounds__(256) void conv2_kernel(const ushort* __restrict__ W,
                                                    const ushort* __restrict__ Bm,
                                                    const float* __restrict__ RES,
                                                    float* __restrict__ OUT) {
  const int b = blockIdx.z;
  const int wid = threadIdx.x >> 6, lane = threadIdx.x & 63;
  const int col = lane & 15, quad = lane >> 4;
  const int m0 = blockIdx.y * 64 + (wid >> 1) * 32;
  const int n0 = blockIdx.x * 64 + (wid & 1) * 32;
  const ushort* Bb = Bm + (size_t)b * (S / 16) * (CIN / 32) * 512;
  const int lofs = col * 32 + quad * 8;
  f32x4 acc[2][2] = {};
  #pragma unroll
  for (int k0 = 0; k0 < CIN; k0 += 32) {
    bf16x8 af[2], bf[2];
    #pragma unroll
    for (int mi = 0; mi < 2; mi++)
      af[mi] = *(const bf16x8*)&W[((size_t)(m0 / 16 + mi) * (CIN / 32) + (k0 >> 5)) * 512 + lofs];
    #pragma unroll
    for (int ni = 0; ni < 2; ni++)
      bf[ni] = *(const bf16x8*)&Bb[((size_t)(n0 / 16 + ni) * (CIN / 32) + (k0 >> 5)) * 512 + lofs];
    #pragma unroll
    for (int mi = 0; mi < 2; mi++)
      #pragma unroll
      for (int ni = 0; ni < 2; ni++)
        acc[mi][ni] = __builtin_amdgcn_mfma_f32_16x16x32_bf16(af[mi], bf[ni], acc[mi][ni], 0, 0, 0);
  }
  const float tc = 0.3f, om = 0.7f, inv = 1.3130643285972254f;
  #pragma unroll
  for (int mi = 0; mi < 2; mi++)
    #pragma unroll
    for (int ni = 0; ni < 2; ni++)
      #pragma unroll
      for (int r = 0; r < 4; r++) {
        const size_t idx = ((size_t)(b * CIN + m0 + mi * 16 + quad * 4 + r)) * S + n0 + ni * 16 + col;
        OUT[idx] = (om * RES[idx] + tc * acc[mi][ni][r]) * inv;
      }
}

// ---------------- launch ----------------
extern "C" void kernel_launch(void* const* d_in, const int* in_sizes, int n_in,
                              void* d_out, int out_size, void* d_ws, size_t ws_size,
                              hipStream_t stream) {
  const float* x = (const float*)d_in[0];
  const float* w_qkv = (const float*)d_in[1];
  const float* w_out = (const float*)d_in[2];
  float* out = (float*)d_out;

  ushort* p = (ushort*)d_ws;
  ushort* wqb = p; p += (size_t)C3 * CIN;
  ushort* wob = p; p += (size_t)CIN * CIN;
  ushort* Qn = p; p += (size_t)2 * NH * S * HD;
  ushort* Kn = p; p += (size_t)2 * NH * S * HD;
  ushort* Vt = p; p += (size_t)2 * NH * S * HD;
  ushort* Yt = p; p += (size_t)2 * S * CIN;
  // Region R: Xt (4.2 MB bf16) dies after conv1_fused; accPb bf16
  // (KSPLIT*2*8*4096*32 ushorts = 16.8 MB) aliases the same region.
  ushort* R = p; p += (size_t)KSPLIT * 2 * NH * S * HD;  // 16.8 MB
  ushort* Xt = R;
  ushort* accPb = R;
  float* lP = (float*)p;  // KSPLIT*2*8*4096 floats = 1 MB

  wnorm_kernel<<<(C3 + CIN) / 4, 256, 0, stream>>>(w_qkv, w_out, wqb, wob);
  xt_kernel<<<dim3(S / 64, CIN / 64, 2), 256, 0, stream>>>(x, Xt);
  conv1_fused_kernel<<<dim3(S / 64, C3 / 64, 2), 256, 0, stream>>>(wqb, Xt, Qn, Kn, Vt);
  attn_kernel<<<(S / 256) * NH * KSPLIT * 2, 256, 0, stream>>>(Qn, Kn, Vt, accPb, lP);
  combine_kernel<<<2048, 256, 0, stream>>>(accPb, lP, Yt);
  conv2_kernel<<<dim3(S / 64, CIN / 64, 2), 256, 0, stream>>>(wob, Yt, x, out);
}

// Round 11
// 143.280 us; speedup vs baseline: 1.0564x; 1.0564x over previous
//
#include <hip/hip_runtime.h>
#include <hip/hip_bf16.h>
#include <math.h>

#define S 4096
#define CIN 256
#define C3 768
#define NH 8
#define HD 32
#define KSPLIT 4

static constexpr float EPS = 1e-4f;

typedef __attribute__((ext_vector_type(8))) __bf16 bf16x8;
typedef __attribute__((ext_vector_type(4))) float f32x4;
typedef __attribute__((ext_vector_type(16))) float f32x16;
typedef __attribute__((ext_vector_type(4))) unsigned u32x4;

static inline __device__ ushort f2bf(float f) {  // RN-even
  unsigned u = __float_as_uint(f);
  return (ushort)((u + 0x7fffu + ((u >> 16) & 1u)) >> 16);
}
static inline __device__ float bf2f(ushort u) {
  return __uint_as_float((unsigned)u << 16);
}

// v_cvt_pk_bf16_f32: dst.lo16 = bf16(lo), dst.hi16 = bf16(hi); RNE (no builtin)
static inline __device__ unsigned cvt_pk_bf16(float lo, float hi) {
  unsigned r;
  asm("v_cvt_pk_bf16_f32 %0, %1, %2" : "=v"(r) : "v"(lo), "v"(hi));
  return r;
}
// v_permlane32_swap_b32: a.hi32lanes <-> b.lo32lanes.
static inline __device__ void plane32_swap(unsigned& a, unsigned& b) {
  asm("v_permlane32_swap_b32 %0, %1" : "+v"(a), "+v"(b));
}

#define EXP2 __builtin_amdgcn_exp2f

// All GEMM operands live in [16 rows][32 ch] = 1KB fragment panels:
//   elem (r, c) of tile -> tile_base + (r&15)*32 + (c&31)
//   frag load = tile_base + col*32 + quad*8  (dense 1KB per instruction)

// Convert one 32x32 QK score tile (D-layout: col=q=lane&31, row=k=(r&3)+8*(r>>2)+4*hi)
// to two PV operand fragments (col/row=q, k = frag*8 elements at 8*hi+j) fully
// in registers: 8 cvt_pk + 4 permlane32_swap. Accumulates the lane's 16 exp
// values into lacc (softmax denominator partial; full denom = lacc +
// shfl_xor(lacc,32)). NOTE (R10 lesson): keep lacc on VALU -- the ones-MFMA
// variant conserved the pipe-busy sum and regressed (issue-bandwidth bound).
static inline __device__ void s_to_pf(const f32x16 s, bf16x8& plo, bf16x8& phi,
                                      float& lacc) {
  float e0 = EXP2(s[0]), e1 = EXP2(s[1]), e2 = EXP2(s[2]), e3 = EXP2(s[3]);
  float e4 = EXP2(s[4]), e5 = EXP2(s[5]), e6 = EXP2(s[6]), e7 = EXP2(s[7]);
  float e8 = EXP2(s[8]), e9 = EXP2(s[9]), e10 = EXP2(s[10]), e11 = EXP2(s[11]);
  float e12 = EXP2(s[12]), e13 = EXP2(s[13]), e14 = EXP2(s[14]), e15 = EXP2(s[15]);
  lacc += (((e0 + e1) + (e2 + e3)) + ((e4 + e5) + (e6 + e7))) +
          (((e8 + e9) + (e10 + e11)) + ((e12 + e13) + (e14 + e15)));
  unsigned c0 = cvt_pk_bf16(e0, e1);
  unsigned c1 = cvt_pk_bf16(e2, e3);
  unsigned c2 = cvt_pk_bf16(e4, e5);
  unsigned c3 = cvt_pk_bf16(e6, e7);
  plane32_swap(c0, c2);
  plane32_swap(c1, c3);
  u32x4 lo4 = {c0, c1, c2, c3};
  plo = __builtin_bit_cast(bf16x8, lo4);
  unsigned c4 = cvt_pk_bf16(e8, e9);
  unsigned c5 = cvt_pk_bf16(e10, e11);
  unsigned c6 = cvt_pk_bf16(e12, e13);
  unsigned c7 = cvt_pk_bf16(e14, e15);
  plane32_swap(c4, c6);
  plane32_swap(c5, c7);
  u32x4 hi4 = {c4, c5, c6, c7};
  phi = __builtin_bit_cast(bf16x8, hi4);
}

// ---------------- weight norm -> 16x32 fragment panels -----------------------
__global__ __launch_bounds__(256) void wnorm_kernel(const float* __restrict__ w_qkv,
                                                    const float* __restrict__ w_out,
                                                    ushort* __restrict__ wqb,
                                                    ushort* __restrict__ wob) {
  const int row = blockIdx.x * 4 + (threadIdx.x >> 6);
  const int lane = threadIdx.x & 63;
  const bool is_q = row < C3;
  const int r2 = is_q ? row : row - C3;
  const float* wr = (is_q ? w_qkv : w_out) + (size_t)r2 * CIN;
  float v[4];
  #pragma unroll
  for (int i = 0; i < 4; i++) v[i] = wr[lane + 64 * i];
  float ss = v[0] * v[0] + v[1] * v[1] + v[2] * v[2] + v[3] * v[3];
  #pragma unroll
  for (int off = 32; off > 0; off >>= 1) ss += __shfl_down(ss, off, 64);
  ss = __shfl(ss, 0, 64);
  const float scale = 1.0f / (sqrtf(ss) + 16.0f * EPS);
  ushort* whr = (is_q ? wqb : wob);
  #pragma unroll
  for (int i = 0; i < 4; i++) {
    const int c = lane + 64 * i;
    whr[((size_t)(r2 >> 4) * (CIN / 32) + (c >> 5)) * 512 + (r2 & 15) * 32 + (c & 31)] =
        f2bf(v[i] * scale);
  }
}

// ---------------- X [b][c][s] fp32 -> Xt 16x32 panels ------------------------
__global__ __launch_bounds__(256) void xt_kernel(const float* __restrict__ X,
                                                 ushort* __restrict__ Xt) {
  const int b = blockIdx.z;
  const int s0 = blockIdx.x * 64, c0 = blockIdx.y * 64;
  __shared__ ushort T[64][72];
  const int tc = threadIdx.x >> 4;
  const int ts = threadIdx.x & 15;
  #pragma unroll
  for (int i = 0; i < 4; i++) {
    const float4 v = *(const float4*)&X[((size_t)(b * CIN + c0 + tc + 16 * i)) * S + s0 + ts * 4];
    ushort4 u;
    u.x = f2bf(v.x); u.y = f2bf(v.y); u.z = f2bf(v.z); u.w = f2bf(v.w);
    *(ushort4*)&T[tc + 16 * i][ts * 4] = u;
  }
  __syncthreads();
  #pragma unroll
  for (int i = 0; i < 4; i++) {
    const int sr = tc + 16 * i;
    const int s = s0 + sr;
    const int c = c0 + ts * 4;
    ushort4 u;
    u.x = T[ts * 4 + 0][sr];
    u.y = T[ts * 4 + 1][sr];
    u.z = T[ts * 4 + 2][sr];
    u.w = T[ts * 4 + 3][sr];
    *(ushort4*)&Xt[(((size_t)b * (S / 16) + (s >> 4)) * (CIN / 32) + (c >> 5)) * 512 +
                   (s & 15) * 32 + (c & 31)] = u;
  }
}

// ---------------- conv1 fused with pixel-norm + layout fan-out (R9) ----------
// A (W) and B (Xt) both read from 16x32 panels: every frag load is dense 1KB.
// Outputs: Q rows [bh][q][HD]; K/V in attn fragment panels (R3 layout).
__global__ __launch_bounds__(256) void conv1_fused_kernel(const ushort* __restrict__ W,
                                                          const ushort* __restrict__ Bm,
                                                          ushort* __restrict__ Qn,
                                                          ushort* __restrict__ Kn,
                                                          ushort* __restrict__ Vt) {
  const int b = blockIdx.z;
  const int wid = threadIdx.x >> 6, lane = threadIdx.x & 63;
  const int col = lane & 15, quad = lane >> 4;
  const int m0 = blockIdx.y * 64 + (wid >> 1) * 32;  // 32-aligned: one head group
  const int n0 = blockIdx.x * 128 + (wid & 1) * 64;
  const ushort* Bb = Bm + (size_t)b * (S / 16) * (CIN / 32) * 512;
  const int lofs = col * 32 + quad * 8;
  f32x4 acc[2][4] = {};
  #pragma unroll
  for (int k0 = 0; k0 < CIN; k0 += 32) {
    bf16x8 af[2], bf[4];
    #pragma unroll
    for (int mi = 0; mi < 2; mi++)
      af[mi] = *(const bf16x8*)&W[((size_t)(m0 / 16 + mi) * (CIN / 32) + (k0 >> 5)) * 512 + lofs];
    #pragma unroll
    for (int ni = 0; ni < 4; ni++)
      bf[ni] = *(const bf16x8*)&Bb[((size_t)(n0 / 16 + ni) * (CIN / 32) + (k0 >> 5)) * 512 + lofs];
    #pragma unroll
    for (int mi = 0; mi < 2; mi++)
      #pragma unroll
      for (int ni = 0; ni < 4; ni++)
        acc[mi][ni] = __builtin_amdgcn_mfma_f32_16x16x32_bf16(af[mi], bf[ni], acc[mi][ni], 0, 0, 0);
  }

  const int g = m0 >> 5;   // 0..23: group; 0-7 Q, 8-15 K, 16-23 V
  const int h = g & 7;
  float rn[4];
  #pragma unroll
  for (int ni = 0; ni < 4; ni++) {
    float ss = 0.f;
    #pragma unroll
    for (int mi = 0; mi < 2; mi++)
      #pragma unroll
      for (int r = 0; r < 4; r++) ss += acc[mi][ni][r] * acc[mi][ni][r];
    ss += __shfl_xor(ss, 16, 64);
    ss += __shfl_xor(ss, 32, 64);
    rn[ni] = rsqrtf(ss * (1.0f / HD) + EPS);
    if (g < 8) rn[ni] *= 0.2550348190698169f;  // log2(e)/sqrt(32) folded into Q
  }

  if (g < 8) {  // Q: row layout [q][HD]
    ushort* dst = Qn + (size_t)(b * NH + h) * S * HD;
    #pragma unroll
    for (int mi = 0; mi < 2; mi++)
      #pragma unroll
      for (int ni = 0; ni < 4; ni++) {
        ushort4 u;
        u.x = f2bf(acc[mi][ni][0] * rn[ni]);
        u.y = f2bf(acc[mi][ni][1] * rn[ni]);
        u.z = f2bf(acc[mi][ni][2] * rn[ni]);
        u.w = f2bf(acc[mi][ni][3] * rn[ni]);
        *(ushort4*)&dst[(size_t)(n0 + ni * 16 + col) * HD + mi * 16 + quad * 4] = u;
      }
  } else if (g < 16) {  // K: attn fragment panels
    ushort* dst = Kn + (size_t)(b * NH + h) * S * HD + (size_t)(n0 >> 5) * 1024;
    #pragma unroll
    for (int mi = 0; mi < 2; mi++)
      #pragma unroll
      for (int ni = 0; ni < 4; ni++) {
        ushort4 u;
        u.x = f2bf(acc[mi][ni][0] * rn[ni]);
        u.y = f2bf(acc[mi][ni][1] * rn[ni]);
        u.z = f2bf(acc[mi][ni][2] * rn[ni]);
        u.w = f2bf(acc[mi][ni][3] * rn[ni]);
        *(ushort4*)&dst[(ni >> 1) * 1024 + mi * 512 + ((ni & 1) * 16 + col) * 16 +
                        (quad >> 1) * 8 + (quad & 1) * 4] = u;
      }
  } else {  // V: attn fragment panels (d = mi*16+quad*4+r, key = n0+ni*16+col)
    ushort* dst = Vt + (size_t)(b * NH + h) * HD * S + (size_t)(n0 >> 6) * 2048;
    #pragma unroll
    for (int mi = 0; mi < 2; mi++)
      #pragma unroll
      for (int ni = 0; ni < 4; ni++)
        #pragma unroll
        for (int r = 0; r < 4; r++)
          dst[ni * 512 + (mi * 16 + quad * 4 + r) * 16 + col] =
              f2bf(acc[mi][ni][r] * rn[ni]);
  }
}

// ---------------- MFMA attention: dual 32x32 q-tiles per wave ----------------
// R9 structure (best measured: attn 54.3 us, total 144.6) with ONE change:
// main loop unrolled 2x so the scheduler gets a 2-iteration window to overlap
// tile-A/B softmax VALU chains with the NEXT iteration's independent QK MFMAs
// (pipe-sum was 76% at unroll 1 -- issue-bound with ~23% dependency stall).
// lacc stays on VALU (R10 disproved ones-MFMA twice). ~96-125 regs at
// __launch_bounds__(256,4); spill tripwire: WRITE_SIZE must stay ~17.4 MB.
// KSPLIT=4, grid 1024 = 4 blocks/CU, bijective XCD swizzle, zero LDS, bf16
// partial output.
__global__ __launch_bounds__(256, 4) void attn_kernel(const ushort* __restrict__ Qn,
                                                      const ushort* __restrict__ Kn,
                                                      const ushort* __restrict__ Vt,
                                                      ushort* __restrict__ accPb,
                                                      float* __restrict__ lP) {
  const int NWG = (S / 256) * NH * KSPLIT * 2;  // 1024
  const int bid = blockIdx.x;
  const int id = (bid & 7) * (NWG / 8) + (bid >> 3);
  const int qt = id & 15;       // 16 q-tiles of 256 rows
  const int grp = id >> 4;      // ((b*KSPLIT + kp) << 3) | h
  const int h = grp & 7;
  const int kp = (grp >> 3) & (KSPLIT - 1);
  const int b = (grp >> 3) / KSPLIT;
  const int wid = threadIdx.x >> 6, lane = threadIdx.x & 63;
  const int ln = lane & 31, hi = lane >> 5;
  const int qA = qt * 256 + wid * 64;   // tile A rows qA..qA+31
  const int qB = qA + 32;               // tile B rows qB..qB+31

  const ushort* Qh = Qn + (size_t)(b * NH + h) * S * HD;

  // Q as B-frag: col=q=ln, ch = half*16 + 8*hi + j
  bf16x8 qfA0 = *(const bf16x8*)&Qh[(size_t)(qA + ln) * HD + hi * 8];
  bf16x8 qfA1 = *(const bf16x8*)&Qh[(size_t)(qA + ln) * HD + 16 + hi * 8];
  bf16x8 qfB0 = *(const bf16x8*)&Qh[(size_t)(qB + ln) * HD + hi * 8];
  bf16x8 qfB1 = *(const bf16x8*)&Qh[(size_t)(qB + ln) * HD + 16 + hi * 8];

  const f32x16 z = {};
  f32x16 accA = {}, accB = {};  // out^T tiles: row=d, col=q
  float laccA = 0.f, laccB = 0.f;

  const int kt0 = kp * (S / KSPLIT);
  // fragment-panel bases; every frag load = base + frag_offset + loff
  const int loff = (ln * 2 + hi) * 8;
  const ushort* Kp = Kn + (size_t)(b * NH + h) * S * HD + (size_t)kt0 * 32 + loff;
  const ushort* Vp = Vt + (size_t)(b * NH + h) * HD * S + (size_t)kt0 * 32 + loff;

  bf16x8 kf0 = *(const bf16x8*)&Kp[0];
  bf16x8 kf1 = *(const bf16x8*)&Kp[512];
  bf16x8 vf0 = *(const bf16x8*)&Vp[0];
  bf16x8 vf1 = *(const bf16x8*)&Vp[512];

  #pragma unroll 2
  for (int it = 0; it < S / KSPLIT / 32; ++it) {   // 32-key steps
    f32x16 sA = __builtin_amdgcn_mfma_f32_32x32x16_bf16(kf0, qfA0, z, 0, 0, 0);
    sA = __builtin_amdgcn_mfma_f32_32x32x16_bf16(kf1, qfA1, sA, 0, 0, 0);
    f32x16 sB = __builtin_amdgcn_mfma_f32_32x32x16_bf16(kf0, qfB0, z, 0, 0, 0);
    sB = __builtin_amdgcn_mfma_f32_32x32x16_bf16(kf1, qfB1, sB, 0, 0, 0);
    Kp += 1024;
    kf0 = *(const bf16x8*)&Kp[0];      // prefetch next tile's K (overread stays in ws)
    kf1 = *(const bf16x8*)&Kp[512];

    bf16x8 pfA0, pfA1;
    s_to_pf(sA, pfA0, pfA1, laccA);
    accA = __builtin_amdgcn_mfma_f32_32x32x16_bf16(vf0, pfA0, accA, 0, 0, 0);
    accA = __builtin_amdgcn_mfma_f32_32x32x16_bf16(vf1, pfA1, accA, 0, 0, 0);

    bf16x8 pfB0, pfB1;
    s_to_pf(sB, pfB0, pfB1, laccB);
    accB = __builtin_amdgcn_mfma_f32_32x32x16_bf16(vf0, pfB0, accB, 0, 0, 0);
    accB = __builtin_amdgcn_mfma_f32_32x32x16_bf16(vf1, pfB1, accB, 0, 0, 0);

    Vp += 1024;
    vf0 = *(const bf16x8*)&Vp[0];      // prefetch next tile's V
    vf1 = *(const bf16x8*)&Vp[512];
  }

  // acc[r]: d = (r&3) + 8*(r>>2) + 4*hi, q = ln; pack f32 pairs -> bf16
  ushort* ap = accPb + ((size_t)((kp * 2 + b) * NH + h)) * S * HD;
  const size_t rowA = (size_t)(qA + ln) * HD;
  const size_t rowB = (size_t)(qB + ln) * HD;
  #pragma unroll
  for (int g = 0; g < 4; g++) {
    uint2 u;
    u.x = cvt_pk_bf16(accA[4 * g + 0], accA[4 * g + 1]);
    u.y = cvt_pk_bf16(accA[4 * g + 2], accA[4 * g + 3]);
    *(uint2*)&ap[rowA + g * 8 + hi * 4] = u;
    uint2 v;
    v.x = cvt_pk_bf16(accB[4 * g + 0], accB[4 * g + 1]);
    v.y = cvt_pk_bf16(accB[4 * g + 2], accB[4 * g + 3]);
    *(uint2*)&ap[rowB + g * 8 + hi * 4] = v;
  }
  const float lsA = laccA + __shfl_xor(laccA, 32, 64);
  const float lsB = laccB + __shfl_xor(laccB, 32, 64);
  if (hi == 0) {
    float* lp = lP + ((size_t)((kp * 2 + b) * NH + h)) * S;
    lp[qA + ln] = lsA;
    lp[qB + ln] = lsB;
  }
}

// ---------------- combine K-split partials (bf16) -> Yt 16x32 panels ---------
__global__ __launch_bounds__(256) void combine_kernel(const ushort* __restrict__ accPb,
                                                      const float* __restrict__ lP,
                                                      ushort* __restrict__ Yt) {
  const int tid = blockIdx.x * 256 + threadIdx.x;
  const int dg = tid & 7;
  const int q = (tid >> 3) & (S - 1);
  const int h = (tid >> 15) & 7;
  const int b = tid >> 18;
  const size_t i0 = ((size_t)(b * NH + h)) * S + q;
  const size_t part = (size_t)2 * NH * S;
  float sx = 0.f, sy = 0.f, sz = 0.f, sw = 0.f, L = 0.f;
  #pragma unroll
  for (int p = 0; p < KSPLIT; p++) {
    const ushort4 a = *(const ushort4*)&accPb[(size_t)p * part * HD + i0 * HD + dg * 4];
    sx += bf2f(a.x); sy += bf2f(a.y); sz += bf2f(a.z); sw += bf2f(a.w);
    L += lP[(size_t)p * part + i0];
  }
  const float rl = 1.0f / L;
  ushort4 o;
  o.x = f2bf(sx * rl);
  o.y = f2bf(sy * rl);
  o.z = f2bf(sz * rl);
  o.w = f2bf(sw * rl);
  // Yt panel: row=q, ch tile = h (c = h*32 + dg*4)
  *(ushort4*)&Yt[(((size_t)b * (S / 16) + (q >> 4)) * (CIN / 32) + h) * 512 +
                 (q & 15) * 32 + dg * 4] = o;
}

// ---------------- conv2: OUT[b][m][s] fp32 = Wo . Yt, fused mp_add -----------
// A (Wo) and B (Yt) from 16x32 panels (dense frag loads). Block = 4 waves
// covering 64m x 64n. Grid (64,4,2) = 512 blocks = 2 blocks/CU (R8/R9 config).
__global__ __launch_bounds__(256) void conv2_kernel(const ushort* __restrict__ W,
                                                    const ushort* __restrict__ Bm,
                                                    const float* __restrict__ RES,
                                                    float* __restrict__ OUT) {
  const int b = blockIdx.z;
  const int wid = threadIdx.x >> 6, lane = threadIdx.x & 63;
  const int col = lane & 15, quad = lane >> 4;
  const int m0 = blockIdx.y * 64 + (wid >> 1) * 32;
  const int n0 = blockIdx.x * 64 + (wid & 1) * 32;
  const ushort* Bb = Bm + (size_t)b * (S / 16) * (CIN / 32) * 512;
  const int lofs = col * 32 + quad * 8;
  f32x4 acc[2][2] = {};
  #pragma unroll
  for (int k0 = 0; k0 < CIN; k0 += 32) {
    bf16x8 af[2], bf[2];
    #pragma unroll
    for (int mi = 0; mi < 2; mi++)
      af[mi] = *(const bf16x8*)&W[((size_t)(m0 / 16 + mi) * (CIN / 32) + (k0 >> 5)) * 512 + lofs];
    #pragma unroll
    for (int ni = 0; ni < 2; ni++)
      bf[ni] = *(const bf16x8*)&Bb[((size_t)(n0 / 16 + ni) * (CIN / 32) + (k0 >> 5)) * 512 + lofs];
    #pragma unroll
    for (int mi = 0; mi < 2; mi++)
      #pragma unroll
      for (int ni = 0; ni < 2; ni++)
        acc[mi][ni] = __builtin_amdgcn_mfma_f32_16x16x32_bf16(af[mi], bf[ni], acc[mi][ni], 0, 0, 0);
  }
  const float tc = 0.3f, om = 0.7f, inv = 1.3130643285972254f;
  #pragma unroll
  for (int mi = 0; mi < 2; mi++)
    #pragma unroll
    for (int ni = 0; ni < 2; ni++)
      #pragma unroll
      for (int r = 0; r < 4; r++) {
        const size_t idx = ((size_t)(b * CIN + m0 + mi * 16 + quad * 4 + r)) * S + n0 + ni * 16 + col;
        OUT[idx] = (om * RES[idx] + tc * acc[mi][ni][r]) * inv;
      }
}

// ---------------- launch ----------------
extern "C" void kernel_launch(void* const* d_in, const int* in_sizes, int n_in,
                              void* d_out, int out_size, void* d_ws, size_t ws_size,
                              hipStream_t stream) {
  const float* x = (const float*)d_in[0];
  const float* w_qkv = (const float*)d_in[1];
  const float* w_out = (const float*)d_in[2];
  float* out = (float*)d_out;

  ushort* p = (ushort*)d_ws;
  ushort* wqb = p; p += (size_t)C3 * CIN;
  ushort* wob = p; p += (size_t)CIN * CIN;
  ushort* Qn = p; p += (size_t)2 * NH * S * HD;
  ushort* Kn = p; p += (size_t)2 * NH * S * HD;
  ushort* Vt = p; p += (size_t)2 * NH * S * HD;
  ushort* Yt = p; p += (size_t)2 * S * CIN;
  // Region R: Xt (4.2 MB bf16) dies after conv1_fused; accPb bf16
  // (KSPLIT*2*8*4096*32 ushorts = 16.8 MB) aliases the same region.
  ushort* R = p; p += (size_t)KSPLIT * 2 * NH * S * HD;  // 16.8 MB
  ushort* Xt = R;
  ushort* accPb = R;
  float* lP = (float*)p;  // KSPLIT*2*8*4096 floats = 1 MB

  wnorm_kernel<<<(C3 + CIN) / 4, 256, 0, stream>>>(w_qkv, w_out, wqb, wob);
  xt_kernel<<<dim3(S / 64, CIN / 64, 2), 256, 0, stream>>>(x, Xt);
  conv1_fused_kernel<<<dim3(S / 128, C3 / 64, 2), 256, 0, stream>>>(wqb, Xt, Qn, Kn, Vt);
  attn_kernel<<<(S / 256) * NH * KSPLIT * 2, 256, 0, stream>>>(Qn, Kn, Vt, accPb, lP);
  combine_kernel<<<2048, 256, 0, stream>>>(accPb, lP, Yt);
  conv2_kernel<<<dim3(S / 64, CIN / 64, 2), 256, 0, stream>>>(wob, Yt, x, out);
}

// Round 12
// 137.681 us; speedup vs baseline: 1.0994x; 1.0407x over previous
//
#include <hip/hip_runtime.h>
#include <hip/hip_bf16.h>
#include <math.h>

#define S 4096
#define CIN 256
#define C3 768
#define NH 8
#define HD 32
#define KSPLIT 4

static constexpr float EPS = 1e-4f;

typedef __attribute__((ext_vector_type(8))) __bf16 bf16x8;
typedef __attribute__((ext_vector_type(4))) float f32x4;
typedef __attribute__((ext_vector_type(16))) float f32x16;
typedef __attribute__((ext_vector_type(4))) unsigned u32x4;

static inline __device__ ushort f2bf(float f) {  // RN-even
  unsigned u = __float_as_uint(f);
  return (ushort)((u + 0x7fffu + ((u >> 16) & 1u)) >> 16);
}
static inline __device__ float bf2f(ushort u) {
  return __uint_as_float((unsigned)u << 16);
}

// v_cvt_pk_bf16_f32: dst.lo16 = bf16(lo), dst.hi16 = bf16(hi); RNE (no builtin)
static inline __device__ unsigned cvt_pk_bf16(float lo, float hi) {
  unsigned r;
  asm("v_cvt_pk_bf16_f32 %0, %1, %2" : "=v"(r) : "v"(lo), "v"(hi));
  return r;
}
// v_permlane32_swap_b32: a.hi32lanes <-> b.lo32lanes.
static inline __device__ void plane32_swap(unsigned& a, unsigned& b) {
  asm("v_permlane32_swap_b32 %0, %1" : "+v"(a), "+v"(b));
}

#define EXP2 __builtin_amdgcn_exp2f

// All GEMM operands live in [16 rows][32 ch] = 1KB fragment panels:
//   elem (r, c) of tile -> tile_base + (r&15)*32 + (c&31)
//   frag load = tile_base + col*32 + quad*8  (dense 1KB per instruction)

// Convert one 32x32 QK score tile (D-layout: col=q=lane&31, row=k=(r&3)+8*(r>>2)+4*hi)
// to two PV operand fragments (col/row=q, k = frag*8 elements at 8*hi+j) fully
// in registers: 8 cvt_pk + 4 permlane32_swap. Accumulates the lane's 16 exp
// values into lacc (softmax denominator partial; full denom = lacc +
// shfl_xor(lacc,32)). NOTE (R10 lesson): keep lacc on VALU -- the ones-MFMA
// variant conserved the pipe-busy sum and regressed (issue-bandwidth bound).
static inline __device__ void s_to_pf(const f32x16 s, bf16x8& plo, bf16x8& phi,
                                      float& lacc) {
  float e0 = EXP2(s[0]), e1 = EXP2(s[1]), e2 = EXP2(s[2]), e3 = EXP2(s[3]);
  float e4 = EXP2(s[4]), e5 = EXP2(s[5]), e6 = EXP2(s[6]), e7 = EXP2(s[7]);
  float e8 = EXP2(s[8]), e9 = EXP2(s[9]), e10 = EXP2(s[10]), e11 = EXP2(s[11]);
  float e12 = EXP2(s[12]), e13 = EXP2(s[13]), e14 = EXP2(s[14]), e15 = EXP2(s[15]);
  lacc += (((e0 + e1) + (e2 + e3)) + ((e4 + e5) + (e6 + e7))) +
          (((e8 + e9) + (e10 + e11)) + ((e12 + e13) + (e14 + e15)));
  unsigned c0 = cvt_pk_bf16(e0, e1);
  unsigned c1 = cvt_pk_bf16(e2, e3);
  unsigned c2 = cvt_pk_bf16(e4, e5);
  unsigned c3 = cvt_pk_bf16(e6, e7);
  plane32_swap(c0, c2);
  plane32_swap(c1, c3);
  u32x4 lo4 = {c0, c1, c2, c3};
  plo = __builtin_bit_cast(bf16x8, lo4);
  unsigned c4 = cvt_pk_bf16(e8, e9);
  unsigned c5 = cvt_pk_bf16(e10, e11);
  unsigned c6 = cvt_pk_bf16(e12, e13);
  unsigned c7 = cvt_pk_bf16(e14, e15);
  plane32_swap(c4, c6);
  plane32_swap(c5, c7);
  u32x4 hi4 = {c4, c5, c6, c7};
  phi = __builtin_bit_cast(bf16x8, hi4);
}

// ---------------- fused weight-norm + X-transpose (one launch) ---------------
// Blocks 0..255: weight norm -> 16x32 fragment panels (wqb, wob).
// Blocks 256..767: X [b][c][s] fp32 -> Xt 16x32 panels (LDS transpose).
// Independent work fused to cut kernel count (launch ramp + bubbles dominate
// the small-kernel stack: non-attn floors sum to ~17us but measured ~89us).
__global__ __launch_bounds__(256) void wnxt_kernel(const float* __restrict__ w_qkv,
                                                   const float* __restrict__ w_out,
                                                   ushort* __restrict__ wqb,
                                                   ushort* __restrict__ wob,
                                                   const float* __restrict__ X,
                                                   ushort* __restrict__ Xt) {
  __shared__ ushort T[64][72];
  if (blockIdx.x < 256) {
    const int row = blockIdx.x * 4 + (threadIdx.x >> 6);
    const int lane = threadIdx.x & 63;
    const bool is_q = row < C3;
    const int r2 = is_q ? row : row - C3;
    const float* wr = (is_q ? w_qkv : w_out) + (size_t)r2 * CIN;
    float v[4];
    #pragma unroll
    for (int i = 0; i < 4; i++) v[i] = wr[lane + 64 * i];
    float ss = v[0] * v[0] + v[1] * v[1] + v[2] * v[2] + v[3] * v[3];
    #pragma unroll
    for (int off = 32; off > 0; off >>= 1) ss += __shfl_down(ss, off, 64);
    ss = __shfl(ss, 0, 64);
    const float scale = 1.0f / (sqrtf(ss) + 16.0f * EPS);
    ushort* whr = (is_q ? wqb : wob);
    #pragma unroll
    for (int i = 0; i < 4; i++) {
      const int c = lane + 64 * i;
      whr[((size_t)(r2 >> 4) * (CIN / 32) + (c >> 5)) * 512 + (r2 & 15) * 32 + (c & 31)] =
          f2bf(v[i] * scale);
    }
  } else {
    const int bid = blockIdx.x - 256;           // 512 xt blocks: 64 x 4 x 2
    const int s0 = (bid & 63) * 64;
    const int c0 = ((bid >> 6) & 3) * 64;
    const int b = bid >> 8;
    const int tc = threadIdx.x >> 4;
    const int ts = threadIdx.x & 15;
    #pragma unroll
    for (int i = 0; i < 4; i++) {
      const float4 v = *(const float4*)&X[((size_t)(b * CIN + c0 + tc + 16 * i)) * S + s0 + ts * 4];
      ushort4 u;
      u.x = f2bf(v.x); u.y = f2bf(v.y); u.z = f2bf(v.z); u.w = f2bf(v.w);
      *(ushort4*)&T[tc + 16 * i][ts * 4] = u;
    }
    __syncthreads();
    #pragma unroll
    for (int i = 0; i < 4; i++) {
      const int sr = tc + 16 * i;
      const int s = s0 + sr;
      const int c = c0 + ts * 4;
      ushort4 u;
      u.x = T[ts * 4 + 0][sr];
      u.y = T[ts * 4 + 1][sr];
      u.z = T[ts * 4 + 2][sr];
      u.w = T[ts * 4 + 3][sr];
      *(ushort4*)&Xt[(((size_t)b * (S / 16) + (s >> 4)) * (CIN / 32) + (c >> 5)) * 512 +
                     (s & 15) * 32 + (c & 31)] = u;
    }
  }
}

// ---------------- conv1 fused with pixel-norm + layout fan-out (R9) ----------
// A (W) and B (Xt) both read from 16x32 panels: every frag load is dense 1KB.
// Outputs: Q rows [bh][q][HD]; K/V in attn fragment panels (R3 layout).
__global__ __launch_bounds__(256) void conv1_fused_kernel(const ushort* __restrict__ W,
                                                          const ushort* __restrict__ Bm,
                                                          ushort* __restrict__ Qn,
                                                          ushort* __restrict__ Kn,
                                                          ushort* __restrict__ Vt) {
  const int b = blockIdx.z;
  const int wid = threadIdx.x >> 6, lane = threadIdx.x & 63;
  const int col = lane & 15, quad = lane >> 4;
  const int m0 = blockIdx.y * 64 + (wid >> 1) * 32;  // 32-aligned: one head group
  const int n0 = blockIdx.x * 128 + (wid & 1) * 64;
  const ushort* Bb = Bm + (size_t)b * (S / 16) * (CIN / 32) * 512;
  const int lofs = col * 32 + quad * 8;
  f32x4 acc[2][4] = {};
  #pragma unroll
  for (int k0 = 0; k0 < CIN; k0 += 32) {
    bf16x8 af[2], bf[4];
    #pragma unroll
    for (int mi = 0; mi < 2; mi++)
      af[mi] = *(const bf16x8*)&W[((size_t)(m0 / 16 + mi) * (CIN / 32) + (k0 >> 5)) * 512 + lofs];
    #pragma unroll
    for (int ni = 0; ni < 4; ni++)
      bf[ni] = *(const bf16x8*)&Bb[((size_t)(n0 / 16 + ni) * (CIN / 32) + (k0 >> 5)) * 512 + lofs];
    #pragma unroll
    for (int mi = 0; mi < 2; mi++)
      #pragma unroll
      for (int ni = 0; ni < 4; ni++)
        acc[mi][ni] = __builtin_amdgcn_mfma_f32_16x16x32_bf16(af[mi], bf[ni], acc[mi][ni], 0, 0, 0);
  }

  const int g = m0 >> 5;   // 0..23: group; 0-7 Q, 8-15 K, 16-23 V
  const int h = g & 7;
  float rn[4];
  #pragma unroll
  for (int ni = 0; ni < 4; ni++) {
    float ss = 0.f;
    #pragma unroll
    for (int mi = 0; mi < 2; mi++)
      #pragma unroll
      for (int r = 0; r < 4; r++) ss += acc[mi][ni][r] * acc[mi][ni][r];
    ss += __shfl_xor(ss, 16, 64);
    ss += __shfl_xor(ss, 32, 64);
    rn[ni] = rsqrtf(ss * (1.0f / HD) + EPS);
    if (g < 8) rn[ni] *= 0.2550348190698169f;  // log2(e)/sqrt(32) folded into Q
  }

  if (g < 8) {  // Q: row layout [q][HD]
    ushort* dst = Qn + (size_t)(b * NH + h) * S * HD;
    #pragma unroll
    for (int mi = 0; mi < 2; mi++)
      #pragma unroll
      for (int ni = 0; ni < 4; ni++) {
        ushort4 u;
        u.x = f2bf(acc[mi][ni][0] * rn[ni]);
        u.y = f2bf(acc[mi][ni][1] * rn[ni]);
        u.z = f2bf(acc[mi][ni][2] * rn[ni]);
        u.w = f2bf(acc[mi][ni][3] * rn[ni]);
        *(ushort4*)&dst[(size_t)(n0 + ni * 16 + col) * HD + mi * 16 + quad * 4] = u;
      }
  } else if (g < 16) {  // K: attn fragment panels
    ushort* dst = Kn + (size_t)(b * NH + h) * S * HD + (size_t)(n0 >> 5) * 1024;
    #pragma unroll
    for (int mi = 0; mi < 2; mi++)
      #pragma unroll
      for (int ni = 0; ni < 4; ni++) {
        ushort4 u;
        u.x = f2bf(acc[mi][ni][0] * rn[ni]);
        u.y = f2bf(acc[mi][ni][1] * rn[ni]);
        u.z = f2bf(acc[mi][ni][2] * rn[ni]);
        u.w = f2bf(acc[mi][ni][3] * rn[ni]);
        *(ushort4*)&dst[(ni >> 1) * 1024 + mi * 512 + ((ni & 1) * 16 + col) * 16 +
                        (quad >> 1) * 8 + (quad & 1) * 4] = u;
      }
  } else {  // V: attn fragment panels (d = mi*16+quad*4+r, key = n0+ni*16+col)
    ushort* dst = Vt + (size_t)(b * NH + h) * HD * S + (size_t)(n0 >> 6) * 2048;
    #pragma unroll
    for (int mi = 0; mi < 2; mi++)
      #pragma unroll
      for (int ni = 0; ni < 4; ni++)
        #pragma unroll
        for (int r = 0; r < 4; r++)
          dst[ni * 512 + (mi * 16 + quad * 4 + r) * 16 + col] =
              f2bf(acc[mi][ni][r] * rn[ni]);
  }
}

// ---------------- MFMA attention: dual 32x32 q-tiles per wave (R11) ----------
// Best measured: attn 53.8 us. Dual q-tiles share K/V frags (2x ILP), unroll 2
// for cross-iteration scheduling, lacc on VALU (R10 disproved ones-MFMA),
// bf16 partial output. __launch_bounds__(256,4) -- DO NOT raise waves/EU
// (VGPR+AGPR unified file; R2/R4 spilled at (256,8)). KSPLIT=4, grid 1024 =
// 4 blocks/CU, bijective XCD swizzle, zero LDS.
__global__ __launch_bounds__(256, 4) void attn_kernel(const ushort* __restrict__ Qn,
                                                      const ushort* __restrict__ Kn,
                                                      const ushort* __restrict__ Vt,
                                                      ushort* __restrict__ accPb,
                                                      float* __restrict__ lP) {
  const int NWG = (S / 256) * NH * KSPLIT * 2;  // 1024
  const int bid = blockIdx.x;
  const int id = (bid & 7) * (NWG / 8) + (bid >> 3);
  const int qt = id & 15;       // 16 q-tiles of 256 rows
  const int grp = id >> 4;      // ((b*KSPLIT + kp) << 3) | h
  const int h = grp & 7;
  const int kp = (grp >> 3) & (KSPLIT - 1);
  const int b = (grp >> 3) / KSPLIT;
  const int wid = threadIdx.x >> 6, lane = threadIdx.x & 63;
  const int ln = lane & 31, hi = lane >> 5;
  const int qA = qt * 256 + wid * 64;   // tile A rows qA..qA+31
  const int qB = qA + 32;               // tile B rows qB..qB+31

  const ushort* Qh = Qn + (size_t)(b * NH + h) * S * HD;

  // Q as B-frag: col=q=ln, ch = half*16 + 8*hi + j
  bf16x8 qfA0 = *(const bf16x8*)&Qh[(size_t)(qA + ln) * HD + hi * 8];
  bf16x8 qfA1 = *(const bf16x8*)&Qh[(size_t)(qA + ln) * HD + 16 + hi * 8];
  bf16x8 qfB0 = *(const bf16x8*)&Qh[(size_t)(qB + ln) * HD + hi * 8];
  bf16x8 qfB1 = *(const bf16x8*)&Qh[(size_t)(qB + ln) * HD + 16 + hi * 8];

  const f32x16 z = {};
  f32x16 accA = {}, accB = {};  // out^T tiles: row=d, col=q
  float laccA = 0.f, laccB = 0.f;

  const int kt0 = kp * (S / KSPLIT);
  // fragment-panel bases; every frag load = base + frag_offset + loff
  const int loff = (ln * 2 + hi) * 8;
  const ushort* Kp = Kn + (size_t)(b * NH + h) * S * HD + (size_t)kt0 * 32 + loff;
  const ushort* Vp = Vt + (size_t)(b * NH + h) * HD * S + (size_t)kt0 * 32 + loff;

  bf16x8 kf0 = *(const bf16x8*)&Kp[0];
  bf16x8 kf1 = *(const bf16x8*)&Kp[512];
  bf16x8 vf0 = *(const bf16x8*)&Vp[0];
  bf16x8 vf1 = *(const bf16x8*)&Vp[512];

  #pragma unroll 2
  for (int it = 0; it < S / KSPLIT / 32; ++it) {   // 32-key steps
    f32x16 sA = __builtin_amdgcn_mfma_f32_32x32x16_bf16(kf0, qfA0, z, 0, 0, 0);
    sA = __builtin_amdgcn_mfma_f32_32x32x16_bf16(kf1, qfA1, sA, 0, 0, 0);
    f32x16 sB = __builtin_amdgcn_mfma_f32_32x32x16_bf16(kf0, qfB0, z, 0, 0, 0);
    sB = __builtin_amdgcn_mfma_f32_32x32x16_bf16(kf1, qfB1, sB, 0, 0, 0);
    Kp += 1024;
    kf0 = *(const bf16x8*)&Kp[0];      // prefetch next tile's K (overread stays in ws)
    kf1 = *(const bf16x8*)&Kp[512];

    bf16x8 pfA0, pfA1;
    s_to_pf(sA, pfA0, pfA1, laccA);
    accA = __builtin_amdgcn_mfma_f32_32x32x16_bf16(vf0, pfA0, accA, 0, 0, 0);
    accA = __builtin_amdgcn_mfma_f32_32x32x16_bf16(vf1, pfA1, accA, 0, 0, 0);

    bf16x8 pfB0, pfB1;
    s_to_pf(sB, pfB0, pfB1, laccB);
    accB = __builtin_amdgcn_mfma_f32_32x32x16_bf16(vf0, pfB0, accB, 0, 0, 0);
    accB = __builtin_amdgcn_mfma_f32_32x32x16_bf16(vf1, pfB1, accB, 0, 0, 0);

    Vp += 1024;
    vf0 = *(const bf16x8*)&Vp[0];      // prefetch next tile's V
    vf1 = *(const bf16x8*)&Vp[512];
  }

  // acc[r]: d = (r&3) + 8*(r>>2) + 4*hi, q = ln; pack f32 pairs -> bf16
  ushort* ap = accPb + ((size_t)((kp * 2 + b) * NH + h)) * S * HD;
  const size_t rowA = (size_t)(qA + ln) * HD;
  const size_t rowB = (size_t)(qB + ln) * HD;
  #pragma unroll
  for (int g = 0; g < 4; g++) {
    uint2 u;
    u.x = cvt_pk_bf16(accA[4 * g + 0], accA[4 * g + 1]);
    u.y = cvt_pk_bf16(accA[4 * g + 2], accA[4 * g + 3]);
    *(uint2*)&ap[rowA + g * 8 + hi * 4] = u;
    uint2 v;
    v.x = cvt_pk_bf16(accB[4 * g + 0], accB[4 * g + 1]);
    v.y = cvt_pk_bf16(accB[4 * g + 2], accB[4 * g + 3]);
    *(uint2*)&ap[rowB + g * 8 + hi * 4] = v;
  }
  const float lsA = laccA + __shfl_xor(laccA, 32, 64);
  const float lsB = laccB + __shfl_xor(laccB, 32, 64);
  if (hi == 0) {
    float* lp = lP + ((size_t)((kp * 2 + b) * NH + h)) * S;
    lp[qA + ln] = lsA;
    lp[qB + ln] = lsB;
  }
}

// ---------------- conv2 with FUSED combine: OUT = Wo . (sum accPb / L) -------
// B-fragments rebuilt from bf16 K-split partials in-register: per (k-tile=head
// h, ni): 4 dense 16B loads + unpack/sum + x(1/L) + cvt_pk. Same sum order and
// RNE rounding as the old combine kernel -> numerically identical. Eliminates
// the combine launch and the Yt write+read. RES prefetched before the K-loop
// (T14) so the residual's HBM latency hides under the GEMM.
// Grid (64,4,2) = 512 blocks = 2 blocks/CU.
__global__ __launch_bounds__(256) void conv2_kernel(const ushort* __restrict__ W,
                                                    const ushort* __restrict__ accPb,
                                                    const float* __restrict__ lP,
                                                    const float* __restrict__ RES,
                                                    float* __restrict__ OUT) {
  const int b = blockIdx.z;
  const int wid = threadIdx.x >> 6, lane = threadIdx.x & 63;
  const int col = lane & 15, quad = lane >> 4;
  const int m0 = blockIdx.y * 64 + (wid >> 1) * 32;
  const int n0 = blockIdx.x * 64 + (wid & 1) * 32;
  const int lofs = col * 32 + quad * 8;
  const size_t part = (size_t)2 * NH * S;

  // T14: issue residual loads first; they complete during the K-loop.
  float res[2][2][4];
  #pragma unroll
  for (int mi = 0; mi < 2; mi++)
    #pragma unroll
    for (int ni = 0; ni < 2; ni++)
      #pragma unroll
      for (int r = 0; r < 4; r++)
        res[mi][ni][r] =
            RES[((size_t)(b * CIN + m0 + mi * 16 + quad * 4 + r)) * S + n0 + ni * 16 + col];

  f32x4 acc[2][2] = {};
  #pragma unroll
  for (int k0 = 0; k0 < CIN; k0 += 32) {
    const int h = k0 >> 5;   // each 32-ch k-tile is exactly one head
    bf16x8 af[2], bf[2];
    #pragma unroll
    for (int mi = 0; mi < 2; mi++)
      af[mi] = *(const bf16x8*)&W[((size_t)(m0 / 16 + mi) * (CIN / 32) + h) * 512 + lofs];
    #pragma unroll
    for (int ni = 0; ni < 2; ni++) {
      const int q = n0 + ni * 16 + col;
      const size_t i0 = ((size_t)(b * NH + h)) * S + q;
      float L = 0.f;
      float e0 = 0.f, e1 = 0.f, e2 = 0.f, e3 = 0.f;
      float e4 = 0.f, e5 = 0.f, e6 = 0.f, e7 = 0.f;
      #pragma unroll
      for (int p = 0; p < KSPLIT; p++) {
        const uint4 a = *(const uint4*)&accPb[(size_t)p * part * HD + i0 * HD + quad * 8];
        e0 += __uint_as_float(a.x << 16);
        e1 += __uint_as_float(a.x & 0xffff0000u);
        e2 += __uint_as_float(a.y << 16);
        e3 += __uint_as_float(a.y & 0xffff0000u);
        e4 += __uint_as_float(a.z << 16);
        e5 += __uint_as_float(a.z & 0xffff0000u);
        e6 += __uint_as_float(a.w << 16);
        e7 += __uint_as_float(a.w & 0xffff0000u);
        L += lP[(size_t)p * part + i0];
      }
      const float rl = 1.0f / L;
      u32x4 pk;
      pk[0] = cvt_pk_bf16(e0 * rl, e1 * rl);
      pk[1] = cvt_pk_bf16(e2 * rl, e3 * rl);
      pk[2] = cvt_pk_bf16(e4 * rl, e5 * rl);
      pk[3] = cvt_pk_bf16(e6 * rl, e7 * rl);
      bf[ni] = __builtin_bit_cast(bf16x8, pk);
    }
    #pragma unroll
    for (int mi = 0; mi < 2; mi++)
      #pragma unroll
      for (int ni = 0; ni < 2; ni++)
        acc[mi][ni] = __builtin_amdgcn_mfma_f32_16x16x32_bf16(af[mi], bf[ni], acc[mi][ni], 0, 0, 0);
  }
  const float tc = 0.3f, om = 0.7f, inv = 1.3130643285972254f;
  #pragma unroll
  for (int mi = 0; mi < 2; mi++)
    #pragma unroll
    for (int ni = 0; ni < 2; ni++)
      #pragma unroll
      for (int r = 0; r < 4; r++) {
        const size_t idx = ((size_t)(b * CIN + m0 + mi * 16 + quad * 4 + r)) * S + n0 + ni * 16 + col;
        OUT[idx] = (om * res[mi][ni][r] + tc * acc[mi][ni][r]) * inv;
      }
}

// ---------------- launch ----------------
extern "C" void kernel_launch(void* const* d_in, const int* in_sizes, int n_in,
                              void* d_out, int out_size, void* d_ws, size_t ws_size,
                              hipStream_t stream) {
  const float* x = (const float*)d_in[0];
  const float* w_qkv = (const float*)d_in[1];
  const float* w_out = (const float*)d_in[2];
  float* out = (float*)d_out;

  ushort* p = (ushort*)d_ws;
  ushort* wqb = p; p += (size_t)C3 * CIN;
  ushort* wob = p; p += (size_t)CIN * CIN;
  ushort* Qn = p; p += (size_t)2 * NH * S * HD;
  ushort* Kn = p; p += (size_t)2 * NH * S * HD;
  ushort* Vt = p; p += (size_t)2 * NH * S * HD;
  // Region R: Xt (4.2 MB bf16) dies after conv1_fused; accPb bf16
  // (KSPLIT*2*8*4096*32 ushorts = 16.8 MB) aliases the same region.
  ushort* R = p; p += (size_t)KSPLIT * 2 * NH * S * HD;  // 16.8 MB
  ushort* Xt = R;
  ushort* accPb = R;
  float* lP = (float*)p;  // KSPLIT*2*8*4096 floats = 1 MB

  wnxt_kernel<<<256 + 512, 256, 0, stream>>>(w_qkv, w_out, wqb, wob, x, Xt);
  conv1_fused_kernel<<<dim3(S / 128, C3 / 64, 2), 256, 0, stream>>>(wqb, Xt, Qn, Kn, Vt);
  attn_kernel<<<(S / 256) * NH * KSPLIT * 2, 256, 0, stream>>>(Qn, Kn, Vt, accPb, lP);
  conv2_kernel<<<dim3(S / 64, CIN / 64, 2), 256, 0, stream>>>(wob, accPb, lP, x, out);
}